// Round 3
// baseline (75.479 us; speedup 1.0000x reference)
//
#include <hip/hip_runtime.h>

#define OUT_H 256
#define OUT_W 192
#define HWPIX (OUT_H * OUT_W)   // 49152
#define BATCH 64
#define PXL 2                    // pixels per lane

// ---------------- compile-time constants: Li = inv(L), cp = Li·P ----------------

constexpr double cx_ln(double x) {
  int e = 0;
  while (x >= 1.5) { x *= 0.5; ++e; }
  while (x < 0.75) { x *= 2.0; --e; }
  double t = (x - 1.0) / (x + 1.0);
  double t2 = t * t, s = 0.0, term = t;
  for (int k = 0; k < 20; ++k) { s += term / (double)(2 * k + 1); term *= t2; }
  return 2.0 * s + (double)e * 0.6931471805599453094172321214581766;
}

struct Consts {
  float li[28][25];
  float cp[2][28];
};

constexpr Consts make_consts() {
  Consts out{};
  double PX[25] = {}, PY[25] = {};
  for (int n = 0; n < 25; ++n) {
    PX[n] = -1.0 + 0.5 * (double)(n / 5);
    PY[n] = -1.0 + 0.5 * (double)(n % 5);
  }
  double M[28][56] = {};
  for (int i = 0; i < 28; ++i)
    for (int j = 0; j < 56; ++j) M[i][j] = 0.0;
  for (int i = 0; i < 25; ++i) {
    for (int j = 0; j < 25; ++j) {
      double dx = PX[i] - PX[j], dy = PY[i] - PY[j];
      double d2 = dx * dx + dy * dy;
      M[i][j] = (d2 == 0.0) ? 0.0 : d2 * cx_ln(d2);
    }
    M[i][25] = 1.0; M[i][26] = PX[i]; M[i][27] = PY[i];
    M[25][i] = 1.0; M[26][i] = PX[i]; M[27][i] = PY[i];
  }
  for (int i = 0; i < 28; ++i) M[i][28 + i] = 1.0;
  for (int k = 0; k < 28; ++k) {
    int piv = k;
    double mx = M[k][k] < 0.0 ? -M[k][k] : M[k][k];
    for (int r = k + 1; r < 28; ++r) {
      double a = M[r][k] < 0.0 ? -M[r][k] : M[r][k];
      if (a > mx) { mx = a; piv = r; }
    }
    if (piv != k)
      for (int j = 0; j < 56; ++j) { double t = M[k][j]; M[k][j] = M[piv][j]; M[piv][j] = t; }
    double inv = 1.0 / M[k][k];
    for (int j = 0; j < 56; ++j) M[k][j] *= inv;
    for (int r = 0; r < 28; ++r) {
      if (r == k) continue;
      double f = M[r][k];
      if (f != 0.0)
        for (int j = 0; j < 56; ++j) M[r][j] -= f * M[k][j];
    }
  }
  for (int k = 0; k < 28; ++k)
    for (int m = 0; m < 25; ++m) out.li[k][m] = (float)M[k][28 + m];
  for (int axis = 0; axis < 2; ++axis)
    for (int k = 0; k < 28; ++k) {
      double s = 0.0;
      for (int m = 0; m < 25; ++m)
        s += (double)out.li[k][m] * (axis ? PY[m] : PX[m]);
      out.cp[axis][k] = (float)s;
    }
  return out;
}

constexpr Consts CC = make_consts();

__device__ constexpr float PXf[25] = {
  -1.f,-1.f,-1.f,-1.f,-1.f, -0.5f,-0.5f,-0.5f,-0.5f,-0.5f,
   0.f, 0.f, 0.f, 0.f, 0.f,  0.5f, 0.5f, 0.5f, 0.5f, 0.5f,
   1.f, 1.f, 1.f, 1.f, 1.f };
__device__ constexpr float PYf[25] = {
  -1.f,-0.5f,0.f,0.5f,1.f, -1.f,-0.5f,0.f,0.5f,1.f,
  -1.f,-0.5f,0.f,0.5f,1.f, -1.f,-0.5f,0.f,0.5f,1.f,
  -1.f,-0.5f,0.f,0.5f,1.f };

// ---------------- fused kernel, 2 px/lane ----------------
// Block = 128 pixels x 64 batches, 384 blocks.
// Phase 3: each wave's 224 broadcast ds_read_b128 now serve 128 pixels
// instead of 64 -> LDS issue per output halves vs R2.

__global__ __launch_bounds__(256) void tps_fused(const float* __restrict__ theta,
                                                 float2* __restrict__ out) {
  __shared__ float sth[BATCH * 50];
  __shared__ float sC[BATCH * 56];     // [b][k][axis] interleaved
  const int t = threadIdx.x;

  // ---- phase 1: stage theta (12.8 KB, coalesced float4) ----
  {
    const float4* g4 = (const float4*)theta;
    float4* s4 = (float4*)sth;
#pragma unroll
    for (int i = 0; i < 4; ++i) {
      int idx = t + i * 256;
      if (idx < 800) s4[idx] = g4[idx];
    }
  }
  __syncthreads();

  // ---- phase 2: coefficients (thread owns fixed (b,axis); Li rows uniform) ----
  {
    const int pair = t & 127;
    const int b = pair >> 1, axis = pair & 1;
    const int kg = t >> 7;
    float th[25];
    const float* src = sth + b * 50 + axis * 25;
#pragma unroll
    for (int m = 0; m < 25; ++m) th[m] = src[m];
#pragma unroll
    for (int j = 0; j < 14; ++j) {
      const int k = kg * 14 + j;
      float acc = CC.cp[axis][k];
#pragma unroll
      for (int m = 0; m < 25; ++m) acc += CC.li[k][m] * th[m];
      sC[b * 56 + k * 2 + axis] = acc;
    }
  }
  __syncthreads();

  // ---- phase 3: evaluate, 2 pixels per lane ----
  const int lane = t & 63;
  const int wg = t >> 6;                       // batch group 0..3 (wave-uniform)
  const int pbase = blockIdx.x * (64 * PXL) + lane;

  float U[PXL][28];
#pragma unroll
  for (int q = 0; q < PXL; ++q) {
    const int p = pbase + q * 64;
    const int w = p % OUT_W;
    const int h = p / OUT_W;
    // bit-identical to np.linspace(-1,1,n).astype(float32)
    float gx = (float)(-1.0 + (double)w * (2.0 / 191.0));
    float gy = (float)(-1.0 + (double)h * (2.0 / 255.0));
    if (w == OUT_W - 1) gx = 1.0f;
    if (h == OUT_H - 1) gy = 1.0f;
#pragma unroll
    for (int n = 0; n < 25; ++n) {
      float dx = gx - PXf[n];
      float dy = gy - PYf[n];
      float d2 = dx * dx + dy * dy;
      float u = d2 * __logf(d2);
      U[q][n] = (d2 == 0.0f) ? 0.0f : u;
    }
    U[q][25] = 1.0f; U[q][26] = gx; U[q][27] = gy;
  }

  const float4* cb = (const float4*)sC + wg * 16 * 14;
  float2* op = out + pbase;
#pragma unroll 2
  for (int i = 0; i < 16; ++i) {
    const float4* c4 = cb + i * 14;            // uniform -> ds_read_b128 broadcast
    float px0 = 0.f, py0 = 0.f, px1 = 0.f, py1 = 0.f;
#pragma unroll
    for (int j = 0; j < 14; ++j) {
      float4 c = c4[j];                        // (Cx[2j],Cy[2j],Cx[2j+1],Cy[2j+1])
      px0 += U[0][2*j]   * c.x;  py0 += U[0][2*j]   * c.y;
      px0 += U[0][2*j+1] * c.z;  py0 += U[0][2*j+1] * c.w;
      px1 += U[1][2*j]   * c.x;  py1 += U[1][2*j]   * c.y;
      px1 += U[1][2*j+1] * c.z;  py1 += U[1][2*j+1] * c.w;
    }
    const int b = wg * 16 + i;
    op[b * HWPIX]      = make_float2(px0, py0);
    op[b * HWPIX + 64] = make_float2(px1, py1);
  }
}

// ---------------- launch ----------------

extern "C" void kernel_launch(void* const* d_in, const int* in_sizes, int n_in,
                              void* d_out, int out_size, void* d_ws, size_t ws_size,
                              hipStream_t stream) {
  const float* theta = (const float*)d_in[0];
  float2* out = (float2*)d_out;
  hipLaunchKernelGGL(tps_fused, dim3(HWPIX / (64 * PXL)), dim3(256), 0, stream, theta, out);
}

// Round 5
// 73.253 us; speedup vs baseline: 1.0304x; 1.0304x over previous
//
#include <hip/hip_runtime.h>

#define OUT_H 256
#define OUT_W 192
#define HWPIX (OUT_H * OUT_W)   // 49152
#define BATCH 64

typedef float v2f __attribute__((ext_vector_type(2)));

// ---------------- compile-time constants: Li = inv(L), cp = Li·P ----------------

constexpr double cx_ln(double x) {
  int e = 0;
  while (x >= 1.5) { x *= 0.5; ++e; }
  while (x < 0.75) { x *= 2.0; --e; }
  double t = (x - 1.0) / (x + 1.0);
  double t2 = t * t, s = 0.0, term = t;
  for (int k = 0; k < 20; ++k) { s += term / (double)(2 * k + 1); term *= t2; }
  return 2.0 * s + (double)e * 0.6931471805599453094172321214581766;
}

struct Consts {
  float li[28][25];
  float cp[2][28];
};

constexpr Consts make_consts() {
  Consts out{};
  double PX[25] = {}, PY[25] = {};
  for (int n = 0; n < 25; ++n) {
    PX[n] = -1.0 + 0.5 * (double)(n / 5);
    PY[n] = -1.0 + 0.5 * (double)(n % 5);
  }
  double M[28][56] = {};
  for (int i = 0; i < 28; ++i)
    for (int j = 0; j < 56; ++j) M[i][j] = 0.0;
  for (int i = 0; i < 25; ++i) {
    for (int j = 0; j < 25; ++j) {
      double dx = PX[i] - PX[j], dy = PY[i] - PY[j];
      double d2 = dx * dx + dy * dy;
      M[i][j] = (d2 == 0.0) ? 0.0 : d2 * cx_ln(d2);
    }
    M[i][25] = 1.0; M[i][26] = PX[i]; M[i][27] = PY[i];
    M[25][i] = 1.0; M[26][i] = PX[i]; M[27][i] = PY[i];
  }
  for (int i = 0; i < 28; ++i) M[i][28 + i] = 1.0;
  for (int k = 0; k < 28; ++k) {
    int piv = k;
    double mx = M[k][k] < 0.0 ? -M[k][k] : M[k][k];
    for (int r = k + 1; r < 28; ++r) {
      double a = M[r][k] < 0.0 ? -M[r][k] : M[r][k];
      if (a > mx) { mx = a; piv = r; }
    }
    if (piv != k)
      for (int j = 0; j < 56; ++j) { double t = M[k][j]; M[k][j] = M[piv][j]; M[piv][j] = t; }
    double inv = 1.0 / M[k][k];
    for (int j = 0; j < 56; ++j) M[k][j] *= inv;
    for (int r = 0; r < 28; ++r) {
      if (r == k) continue;
      double f = M[r][k];
      if (f != 0.0)
        for (int j = 0; j < 56; ++j) M[r][j] -= f * M[k][j];
    }
  }
  for (int k = 0; k < 28; ++k)
    for (int m = 0; m < 25; ++m) out.li[k][m] = (float)M[k][28 + m];
  for (int axis = 0; axis < 2; ++axis)
    for (int k = 0; k < 28; ++k) {
      double s = 0.0;
      for (int m = 0; m < 25; ++m)
        s += (double)out.li[k][m] * (axis ? PY[m] : PX[m]);
      out.cp[axis][k] = (float)s;
    }
  return out;
}

constexpr Consts CC = make_consts();

__device__ constexpr float PXf[25] = {
  -1.f,-1.f,-1.f,-1.f,-1.f, -0.5f,-0.5f,-0.5f,-0.5f,-0.5f,
   0.f, 0.f, 0.f, 0.f, 0.f,  0.5f, 0.5f, 0.5f, 0.5f, 0.5f,
   1.f, 1.f, 1.f, 1.f, 1.f };
__device__ constexpr float PYf[25] = {
  -1.f,-0.5f,0.f,0.5f,1.f, -1.f,-0.5f,0.f,0.5f,1.f,
  -1.f,-0.5f,0.f,0.5f,1.f, -1.f,-0.5f,0.f,0.5f,1.f,
  -1.f,-0.5f,0.f,0.5f,1.f };

// ---------------- fused kernel ----------------
// Block = 64 px x 64 batches, 768 blocks = exactly 3 waves/SIMD (balanced).
// Inner product accumulates (px,py) as a 2-wide vector -> v_pk_fma_f32.
// Output stores are non-temporal (write-once stream, keep L2 clean).

__global__ __launch_bounds__(256) void tps_fused(const float* __restrict__ theta,
                                                 v2f* __restrict__ out) {
  __shared__ float sth[BATCH * 50];
  __shared__ float sC[BATCH * 56];     // [b][k][axis]: float2 = (Cx[k], Cy[k])
  const int t = threadIdx.x;

  // ---- phase 1: stage theta (12.8 KB, coalesced float4) ----
  {
    const float4* g4 = (const float4*)theta;
    float4* s4 = (float4*)sth;
#pragma unroll
    for (int i = 0; i < 4; ++i) {
      int idx = t + i * 256;
      if (idx < 800) s4[idx] = g4[idx];
    }
  }
  __syncthreads();

  // ---- phase 2: coefficients (thread owns fixed (b,axis); Li rows uniform) ----
  {
    const int pair = t & 127;
    const int b = pair >> 1, axis = pair & 1;
    const int kg = t >> 7;              // wave-uniform
    float th[25];
    const float* src = sth + b * 50 + axis * 25;
#pragma unroll
    for (int m = 0; m < 25; ++m) th[m] = src[m];
#pragma unroll
    for (int j = 0; j < 14; ++j) {
      const int k = kg * 14 + j;
      float acc = CC.cp[axis][k];
#pragma unroll
      for (int m = 0; m < 25; ++m) acc += CC.li[k][m] * th[m];
      sC[b * 56 + k * 2 + axis] = acc;
    }
  }
  __syncthreads();

  // ---- phase 3: evaluate ----
  const int lane = t & 63;
  const int wg = t >> 6;                // batch group 0..3 (wave-uniform)
  const int p = (blockIdx.x << 6) + lane;   // 64 px/block, never crosses a row
  const int w = p % OUT_W;
  const int h = p / OUT_W;
  // bit-identical to np.linspace(-1,1,n).astype(float32)
  float gx = (float)(-1.0 + (double)w * (2.0 / 191.0));
  float gy = (float)(-1.0 + (double)h * (2.0 / 255.0));
  if (w == OUT_W - 1) gx = 1.0f;
  if (h == OUT_H - 1) gy = 1.0f;

  float U[28];
#pragma unroll
  for (int n = 0; n < 25; ++n) {
    float dx = gx - PXf[n];
    float dy = gy - PYf[n];
    float d2 = dx * dx + dy * dy;
    float u = d2 * __logf(d2);
    U[n] = (d2 == 0.0f) ? 0.0f : u;     // select discards NaN from 0*(-inf)
  }
  U[25] = 1.0f; U[26] = gx; U[27] = gy;

  const float4* cb = (const float4*)sC + wg * 16 * 14;  // 14 float4 per batch
  v2f* op = out + p;
#pragma unroll 4
  for (int i = 0; i < 16; ++i) {
    const float4* c4 = cb + i * 14;     // wave-uniform -> ds_read_b128 broadcast
    v2f acc = {0.f, 0.f};
#pragma unroll
    for (int j = 0; j < 14; ++j) {
      float4 c = c4[j];                 // (Cx[2j],Cy[2j],Cx[2j+1],Cy[2j+1])
      v2f c01 = {c.x, c.y};
      v2f c23 = {c.z, c.w};
      v2f u0 = {U[2 * j], U[2 * j]};
      v2f u1 = {U[2 * j + 1], U[2 * j + 1]};
      acc = __builtin_elementwise_fma(u0, c01, acc);   // -> v_pk_fma_f32
      acc = __builtin_elementwise_fma(u1, c23, acc);
    }
    const int b = wg * 16 + i;
    __builtin_nontemporal_store(acc, op + b * HWPIX);
  }
}

// ---------------- launch ----------------

extern "C" void kernel_launch(void* const* d_in, const int* in_sizes, int n_in,
                              void* d_out, int out_size, void* d_ws, size_t ws_size,
                              hipStream_t stream) {
  const float* theta = (const float*)d_in[0];
  v2f* out = (v2f*)d_out;
  hipLaunchKernelGGL(tps_fused, dim3(HWPIX / 64), dim3(256), 0, stream, theta, out);
}

// Round 6
// 71.553 us; speedup vs baseline: 1.0549x; 1.0238x over previous
//
#include <hip/hip_runtime.h>

#define OUT_H 256
#define OUT_W 192
#define HWPIX (OUT_H * OUT_W)   // 49152
#define BATCH 64

typedef float v2f __attribute__((ext_vector_type(2)));
typedef float v4f __attribute__((ext_vector_type(4)));

// ---------------- compile-time constants: Li = inv(L), cp = Li·P ----------------

constexpr double cx_ln(double x) {
  int e = 0;
  while (x >= 1.5) { x *= 0.5; ++e; }
  while (x < 0.75) { x *= 2.0; --e; }
  double t = (x - 1.0) / (x + 1.0);
  double t2 = t * t, s = 0.0, term = t;
  for (int k = 0; k < 20; ++k) { s += term / (double)(2 * k + 1); term *= t2; }
  return 2.0 * s + (double)e * 0.6931471805599453094172321214581766;
}

struct Consts {
  float li[28][25];
  float cp[2][28];
};

constexpr Consts make_consts() {
  Consts out{};
  double PX[25] = {}, PY[25] = {};
  for (int n = 0; n < 25; ++n) {
    PX[n] = -1.0 + 0.5 * (double)(n / 5);
    PY[n] = -1.0 + 0.5 * (double)(n % 5);
  }
  double M[28][56] = {};
  for (int i = 0; i < 28; ++i)
    for (int j = 0; j < 56; ++j) M[i][j] = 0.0;
  for (int i = 0; i < 25; ++i) {
    for (int j = 0; j < 25; ++j) {
      double dx = PX[i] - PX[j], dy = PY[i] - PY[j];
      double d2 = dx * dx + dy * dy;
      M[i][j] = (d2 == 0.0) ? 0.0 : d2 * cx_ln(d2);
    }
    M[i][25] = 1.0; M[i][26] = PX[i]; M[i][27] = PY[i];
    M[25][i] = 1.0; M[26][i] = PX[i]; M[27][i] = PY[i];
  }
  for (int i = 0; i < 28; ++i) M[i][28 + i] = 1.0;
  for (int k = 0; k < 28; ++k) {
    int piv = k;
    double mx = M[k][k] < 0.0 ? -M[k][k] : M[k][k];
    for (int r = k + 1; r < 28; ++r) {
      double a = M[r][k] < 0.0 ? -M[r][k] : M[r][k];
      if (a > mx) { mx = a; piv = r; }
    }
    if (piv != k)
      for (int j = 0; j < 56; ++j) { double t = M[k][j]; M[k][j] = M[piv][j]; M[piv][j] = t; }
    double inv = 1.0 / M[k][k];
    for (int j = 0; j < 56; ++j) M[k][j] *= inv;
    for (int r = 0; r < 28; ++r) {
      if (r == k) continue;
      double f = M[r][k];
      if (f != 0.0)
        for (int j = 0; j < 56; ++j) M[r][j] -= f * M[k][j];
    }
  }
  for (int k = 0; k < 28; ++k)
    for (int m = 0; m < 25; ++m) out.li[k][m] = (float)M[k][28 + m];
  for (int axis = 0; axis < 2; ++axis)
    for (int k = 0; k < 28; ++k) {
      double s = 0.0;
      for (int m = 0; m < 25; ++m)
        s += (double)out.li[k][m] * (axis ? PY[m] : PX[m]);
      out.cp[axis][k] = (float)s;
    }
  return out;
}

constexpr Consts CC = make_consts();

__device__ constexpr float PXf[25] = {
  -1.f,-1.f,-1.f,-1.f,-1.f, -0.5f,-0.5f,-0.5f,-0.5f,-0.5f,
   0.f, 0.f, 0.f, 0.f, 0.f,  0.5f, 0.5f, 0.5f, 0.5f, 0.5f,
   1.f, 1.f, 1.f, 1.f, 1.f };
__device__ constexpr float PYf[25] = {
  -1.f,-0.5f,0.f,0.5f,1.f, -1.f,-0.5f,0.f,0.5f,1.f,
  -1.f,-0.5f,0.f,0.5f,1.f, -1.f,-0.5f,0.f,0.5f,1.f,
  -1.f,-0.5f,0.f,0.5f,1.f };

// ---------------- fused kernel ----------------
// Block = 128 pixels x 32 batches; grid = 384 px-groups x 2 batch-groups
// = 768 blocks = exactly 3 waves/SIMD (balanced).
// Each wave: 2 px/lane, 8 batches -> 112 broadcast ds_read_b128 (half of R5)
// and 8 full-width float4 nt stores (1 KB/wave-store, was 512 B).

__global__ __launch_bounds__(256) void tps_fused(const float* __restrict__ theta,
                                                 v4f* __restrict__ out4) {
  __shared__ float sth[32 * 50];       // this block's 32 batches of theta
  __shared__ float sC[32 * 56];        // [b][k][axis]: (Cx[k],Cy[k]) pairs
  const int t = threadIdx.x;
  const int pg = blockIdx.x >> 1;      // 0..383: pixel group (128 px)
  const int bg = blockIdx.x & 1;       // 0..1:   batch group (32 batches)

  // ---- phase 1: stage this group's theta (6.4 KB, coalesced float4) ----
  {
    const float4* g4 = (const float4*)theta + bg * 400;
    float4* s4 = (float4*)sth;
#pragma unroll
    for (int i = 0; i < 2; ++i) {
      int idx = t + i * 256;
      if (idx < 400) s4[idx] = g4[idx];
    }
  }
  __syncthreads();

  // ---- phase 2: coefficients. Thread owns (b,axis); k-range wave-uniform ----
  {
    const int pair = t & 63;            // 32 batches x 2 axes
    const int b = pair >> 1, axis = pair & 1;
    const int kg = t >> 6;              // wave id 0..3 -> k in [7kg, 7kg+7)
    float th[25];
    const float* src = sth + b * 50 + axis * 25;
#pragma unroll
    for (int m = 0; m < 25; ++m) th[m] = src[m];
#pragma unroll
    for (int j = 0; j < 7; ++j) {
      const int k = kg * 7 + j;         // wave-uniform -> Li row via s_load
      float acc = CC.cp[axis][k];
#pragma unroll
      for (int m = 0; m < 25; ++m) acc += CC.li[k][m] * th[m];
      sC[b * 56 + k * 2 + axis] = acc;
    }
  }
  __syncthreads();

  // ---- phase 3: evaluate, 2 adjacent pixels per lane, 8 batches per wave ----
  const int lane = t & 63;
  const int wv = t >> 6;                // wave-uniform
  const int p0 = pg * 128 + lane * 2;   // even; pair never crosses a row
  const int w0 = p0 % OUT_W;
  const int h = p0 / OUT_W;
  // bit-identical to np.linspace(-1,1,n).astype(float32)
  float gx0 = (float)(-1.0 + (double)w0 * (2.0 / 191.0));
  float gx1 = (float)(-1.0 + (double)(w0 + 1) * (2.0 / 191.0));
  float gy  = (float)(-1.0 + (double)h * (2.0 / 255.0));
  if (w0 + 1 == OUT_W - 1) gx1 = 1.0f;
  if (h == OUT_H - 1) gy = 1.0f;

  float U0[28], U1[28];
#pragma unroll
  for (int n = 0; n < 25; ++n) {
    float dyv = gy - PYf[n];
    float dy2 = dyv * dyv;
    float dx0 = gx0 - PXf[n];
    float dx1 = gx1 - PXf[n];
    float d20 = dx0 * dx0 + dy2;
    float d21 = dx1 * dx1 + dy2;
    float u0 = d20 * __logf(d20);
    float u1 = d21 * __logf(d21);
    U0[n] = (d20 == 0.0f) ? 0.0f : u0;  // select discards NaN from 0*(-inf)
    U1[n] = (d21 == 0.0f) ? 0.0f : u1;
  }
  U0[25] = 1.0f; U0[26] = gx0; U0[27] = gy;
  U1[25] = 1.0f; U1[26] = gx1; U1[27] = gy;

  const float4* cb = (const float4*)sC + wv * 8 * 14;   // 14 float4 per batch
  // out index in float4 units: batch * (HWPIX/2) + p0/2
  v4f* op = out4 + (size_t)(bg * 32 + wv * 8) * (HWPIX / 2) + (pg * 64 + lane);
#pragma unroll 2
  for (int i = 0; i < 8; ++i) {
    const float4* c4 = cb + i * 14;     // wave-uniform -> ds_read_b128 broadcast
    v2f a0 = {0.f, 0.f}, a1 = {0.f, 0.f};
#pragma unroll
    for (int j = 0; j < 14; ++j) {
      float4 c = c4[j];                 // (Cx[2j],Cy[2j],Cx[2j+1],Cy[2j+1])
      v2f c01 = {c.x, c.y};
      v2f c23 = {c.z, c.w};
      v2f u00 = {U0[2 * j], U0[2 * j]};
      v2f u01 = {U0[2 * j + 1], U0[2 * j + 1]};
      v2f u10 = {U1[2 * j], U1[2 * j]};
      v2f u11 = {U1[2 * j + 1], U1[2 * j + 1]};
      a0 = __builtin_elementwise_fma(u00, c01, a0);    // v_pk_fma_f32
      a0 = __builtin_elementwise_fma(u01, c23, a0);
      a1 = __builtin_elementwise_fma(u10, c01, a1);
      a1 = __builtin_elementwise_fma(u11, c23, a1);
    }
    v4f res = {a0.x, a0.y, a1.x, a1.y}; // (px0,py0,px1,py1) contiguous in output
    __builtin_nontemporal_store(res, op + (size_t)i * (HWPIX / 2));
  }
}

// ---------------- launch ----------------

extern "C" void kernel_launch(void* const* d_in, const int* in_sizes, int n_in,
                              void* d_out, int out_size, void* d_ws, size_t ws_size,
                              hipStream_t stream) {
  const float* theta = (const float*)d_in[0];
  v4f* out4 = (v4f*)d_out;
  hipLaunchKernelGGL(tps_fused, dim3(768), dim3(256), 0, stream, theta, out4);
}